// Round 1
// baseline (862.012 us; speedup 1.0000x reference)
//
#include <hip/hip_runtime.h>
#include <stdint.h>

// ---------------------------------------------------------------------------
// Problem constants
// ---------------------------------------------------------------------------
#define NSEQ 512        // B*N
#define NGATE 512       // 4*HID
#define HIDN 128

// ws byte offsets
#define OFF_PWIH_E 0
#define OFF_PWHH_E (OFF_PWIH_E + 32*512*4)      //  65536
#define OFF_PWIH_D (OFF_PWHH_E + 64*512*4)      // 196608
#define OFF_PWHH_D (OFF_PWIH_D + 64*512*4)      // 327680
#define OFF_BIAS_E (OFF_PWHH_D + 64*512*4)      // 458752
#define OFF_BIAS_D (OFF_BIAS_E + 512*4)         // 460800
#define OFF_W1P    (OFF_BIAS_D + 512*4)         // 462848
#define OFF_W2P    (OFF_W1P + 288*64*4)         // 536576
#define OFF_FLAT   (OFF_W2P + 32*64*4)          // 544768
#define OFF_DOTS   (1024*1024)                  // [32][512][64] f32 = 4 MB

// ---------------------------------------------------------------------------
// Helpers
// ---------------------------------------------------------------------------
static __device__ __forceinline__ uint32_t f2bf(float f) {
  union { float f; uint32_t u; } v; v.f = f;
  uint32_t u = v.u;
  return (u + 0x7FFFu + ((u >> 16) & 1u)) >> 16;   // RNE bf16
}
static __device__ __forceinline__ uint32_t packbf(float a, float b) {
  return f2bf(a) | (f2bf(b) << 16);
}
static __device__ __forceinline__ float bf_lo(uint32_t u) {
  union { uint32_t u; float f; } v; v.u = u << 16; return v.f;
}
static __device__ __forceinline__ float bf_hi(uint32_t u) {
  union { uint32_t u; float f; } v; v.u = u & 0xFFFF0000u; return v.f;
}
static __device__ __forceinline__ float sigmoidf_(float x) {
  return 1.0f / (1.0f + __expf(-x));
}

// ---------------------------------------------------------------------------
// Kernel 0: weight prep (transpose + bf16 pack + bias sums)
// ---------------------------------------------------------------------------
__global__ __launch_bounds__(256) void prep_kernel(
    const float* Wih_e, const float* Whh_e,
    const float* bih_e, const float* bhh_e,
    const float* Wih_d, const float* Whh_d,
    const float* bih_d, const float* bhh_d,
    const float* w1, const float* w2, char* ws) {
  uint32_t* pWih_e = (uint32_t*)(ws + OFF_PWIH_E);
  uint32_t* pWhh_e = (uint32_t*)(ws + OFF_PWHH_E);
  uint32_t* pWih_d = (uint32_t*)(ws + OFF_PWIH_D);
  uint32_t* pWhh_d = (uint32_t*)(ws + OFF_PWHH_D);
  float*    bias_e = (float*)(ws + OFF_BIAS_E);
  float*    bias_d = (float*)(ws + OFF_BIAS_D);
  uint32_t* w1p    = (uint32_t*)(ws + OFF_W1P);
  uint32_t* w2p    = (uint32_t*)(ws + OFF_W2P);

  int idx = blockIdx.x * 256 + threadIdx.x;
  if (idx < 32*512) {                             // pWih_e [k2][g], in=64
    int k2 = idx >> 9, g = idx & 511;
    pWih_e[idx] = packbf(Wih_e[g*64 + 2*k2], Wih_e[g*64 + 2*k2 + 1]);
    return;
  }
  idx -= 32*512;
  if (idx < 64*512) {                             // pWhh_e, in=128
    int k2 = idx >> 9, g = idx & 511;
    pWhh_e[idx] = packbf(Whh_e[g*128 + 2*k2], Whh_e[g*128 + 2*k2 + 1]);
    return;
  }
  idx -= 64*512;
  if (idx < 64*512) {                             // pWih_d, in=128
    int k2 = idx >> 9, g = idx & 511;
    pWih_d[idx] = packbf(Wih_d[g*128 + 2*k2], Wih_d[g*128 + 2*k2 + 1]);
    return;
  }
  idx -= 64*512;
  if (idx < 64*512) {                             // pWhh_d, in=128
    int k2 = idx >> 9, g = idx & 511;
    pWhh_d[idx] = packbf(Whh_d[g*128 + 2*k2], Whh_d[g*128 + 2*k2 + 1]);
    return;
  }
  idx -= 64*512;
  if (idx < 512) { bias_e[idx] = bih_e[idx] + bhh_e[idx]; return; }
  idx -= 512;
  if (idx < 512) { bias_d[idx] = bih_d[idx] + bhh_d[idx]; return; }
  idx -= 512;
  if (idx < 288*64) {                             // w1p [i2][c]; i = c'*9+tap
    int i2 = idx >> 6, c = idx & 63;
    w1p[idx] = packbf(w1[c*576 + 2*i2], w1[c*576 + 2*i2 + 1]);
    return;
  }
  idx -= 288*64;
  if (idx < 32*64) {                              // w2p [c2][d]
    int c2 = idx >> 6, d = idx & 63;
    w2p[idx] = packbf(w2[d*64 + 2*c2], w2[d*64 + 2*c2 + 1]);
    return;
  }
}
#define PREP_TOTAL (32*512 + 3*64*512 + 512 + 512 + 288*64 + 32*64)

// ---------------------------------------------------------------------------
// Kernel 1: point math -> gt (output 1) + flat indices
// ---------------------------------------------------------------------------
__global__ __launch_bounds__(256) void points_kernel(
    const float* mask_point, float* out_gt, int* flat) {
  int p = blockIdx.x * 256 + threadIdx.x;
  if (p >= 16384) return;
  float mx = mask_point[p*2 + 0];
  float my = mask_point[p*2 + 1];
  float fx = fminf(mx * 0.25f, 127.0f);   // /4.0 is exact scaling
  float fy = fminf(my * 0.25f, 127.0f);
  out_gt[p*2 + 0] = fx * 4.0f;
  out_gt[p*2 + 1] = fy * 4.0f;
  // fy*128 is exact (power of two) so fma == mul+add bit-exactly
  flat[p] = (int)(__fmaf_rn(fy, 128.0f, fx));
}

// ---------------------------------------------------------------------------
// Kernel 2: fused gathered conv (3x3 conv -> ReLU -> 1x1 conv) at points only
// Each block: stages bf16 weights in LDS, processes 32 points.
// ---------------------------------------------------------------------------
__global__ __launch_bounds__(256) void conv_gather_kernel(
    const float* x, const int* point_mask,
    const float* conv1_b, const float* conv2_b,
    const char* ws_ro, float* dots, const int* flat) {
  __shared__ uint32_t w1s[288*64];   // 73728 B
  __shared__ uint32_t w2s[32*64];    //  8192 B
  __shared__ float patch[576];
  __shared__ float tl[64];
  __shared__ float part[256];

  const uint32_t* w1p = (const uint32_t*)(ws_ro + OFF_W1P);
  const uint32_t* w2p = (const uint32_t*)(ws_ro + OFF_W2P);
  int tid = threadIdx.x;
  for (int i = tid; i < 288*64; i += 256) w1s[i] = w1p[i];
  for (int i = tid; i < 32*64;  i += 256) w2s[i] = w2p[i];

  int c = tid & 63, q = tid >> 6;

  for (int pt = 0; pt < 32; ++pt) {
    int p  = blockIdx.x * 32 + pt;
    int bn = p >> 5, k = p & 31;
    int b  = bn >> 5;
    int fl = flat[p];
    int hh = fl >> 7, ww = fl & 127;

    __syncthreads();   // protect patch/tl from previous iteration's readers
    for (int idx = tid; idx < 576; idx += 256) {
      int cp = idx / 9, j = idx - cp*9;
      int dy = j / 3 - 1, dx = j - (j/3)*3 - 1;
      int yy = hh + dy, xx = ww + dx;
      float v = 0.0f;
      if (yy >= 0 && yy < 128 && xx >= 0 && xx < 128)
        v = x[((b*64 + cp)*128 + yy)*128 + xx];
      patch[idx] = v;
    }
    __syncthreads();

    // conv1: thread (q,c) computes a quarter-K partial for channel c
    float acc = 0.0f;
    int i20 = q * 72;
    #pragma unroll 8
    for (int i2 = i20; i2 < i20 + 72; ++i2) {
      uint32_t u = w1s[i2*64 + c];
      float2 pp = *(const float2*)&patch[2*i2];
      acc += bf_lo(u) * pp.x + bf_hi(u) * pp.y;
    }
    part[tid] = acc;
    __syncthreads();
    if (tid < 64) {
      float s = part[tid] + part[64+tid] + part[128+tid] + part[192+tid]
              + conv1_b[tid];
      tl[tid] = fmaxf(s, 0.0f);
    }
    __syncthreads();

    // conv2 (1x1): thread (q,d) partial over 8 c-pairs
    float acc2 = 0.0f;
    int c20 = q * 8;
    #pragma unroll
    for (int c2 = c20; c2 < c20 + 8; ++c2) {
      uint32_t u = w2s[c2*64 + c];
      float2 tt = *(const float2*)&tl[2*c2];
      acc2 += bf_lo(u) * tt.x + bf_hi(u) * tt.y;
    }
    part[tid] = acc2;
    __syncthreads();
    if (tid < 64) {
      float v = part[tid] + part[64+tid] + part[128+tid] + part[192+tid]
              + conv2_b[tid];
      v *= (float)point_mask[p];
      dots[(k*NSEQ + bn)*64 + tid] = v;   // time-major [k][bn][d]
    }
  }
}

// ---------------------------------------------------------------------------
// Kernel 3: encoder LSTM + decoder LSTM + MLP head.
// 128 blocks x 256 threads; each block owns 4 independent sequences.
// Thread t computes gates {t, t+256} for all 4 sequences.
// ---------------------------------------------------------------------------
__global__ __launch_bounds__(256) void lstm_head_kernel(
    const char* ws_ro,
    const float* W1, const float* b1, const float* W2, const float* b2,
    float* out_kp) {
  const float*    dots   = (const float*)(ws_ro + OFF_DOTS);
  const uint32_t* pWih_e = (const uint32_t*)(ws_ro + OFF_PWIH_E);
  const uint32_t* pWhh_e = (const uint32_t*)(ws_ro + OFF_PWHH_E);
  const uint32_t* pWih_d = (const uint32_t*)(ws_ro + OFF_PWIH_D);
  const uint32_t* pWhh_d = (const uint32_t*)(ws_ro + OFF_PWHH_D);
  const float*    bias_e = (const float*)(ws_ro + OFF_BIAS_E);
  const float*    bias_d = (const float*)(ws_ro + OFF_BIAS_D);

  __shared__ float enc_s[32][4][HIDN];   // 64 KB
  __shared__ float hb[4][HIDN];
  __shared__ float cb[4][HIDN];
  __shared__ float xb[4][64];
  __shared__ float gb[4][NGATE];         // 8 KB
  __shared__ float W1T[HIDN*64];         // 32 KB, [u][j]
  __shared__ float hid[4][64];

  int tid = threadIdx.x;
  int bn0 = blockIdx.x * 4;

  for (int i = tid; i < 64*HIDN; i += 256) {
    int j = i >> 7, u = i & 127;       // W1 is [j][u] row-major
    W1T[u*64 + j] = W1[i];
  }
  for (int i = tid; i < 4*HIDN; i += 256) {
    (&hb[0][0])[i] = 0.0f;
    (&cb[0][0])[i] = 0.0f;
  }
  float be0 = bias_e[tid], be1 = bias_e[tid + 256];
  float bd0 = bias_d[tid], bd1 = bias_d[tid + 256];
  __syncthreads();

  // ----------------- encoder -----------------
  for (int t = 0; t < 32; ++t) {
    {
      int s = tid >> 6, d = tid & 63;
      xb[s][d] = dots[(t*NSEQ + bn0 + s)*64 + d];
    }
    __syncthreads();

    float a0[4] = {be0, be0, be0, be0};
    float a1[4] = {be1, be1, be1, be1};
    #pragma unroll 8
    for (int k2 = 0; k2 < 32; ++k2) {          // x contribution (in=64)
      uint32_t u0 = pWih_e[k2*512 + tid];
      uint32_t u1 = pWih_e[k2*512 + tid + 256];
      float w0a = bf_lo(u0), w0b = bf_hi(u0);
      float w1a = bf_lo(u1), w1b = bf_hi(u1);
      #pragma unroll
      for (int s = 0; s < 4; ++s) {
        float2 xv = *(const float2*)&xb[s][2*k2];
        a0[s] += w0a*xv.x + w0b*xv.y;
        a1[s] += w1a*xv.x + w1b*xv.y;
      }
    }
    #pragma unroll 8
    for (int k2 = 0; k2 < 64; ++k2) {          // h contribution
      uint32_t u0 = pWhh_e[k2*512 + tid];
      uint32_t u1 = pWhh_e[k2*512 + tid + 256];
      float w0a = bf_lo(u0), w0b = bf_hi(u0);
      float w1a = bf_lo(u1), w1b = bf_hi(u1);
      #pragma unroll
      for (int s = 0; s < 4; ++s) {
        float2 hv = *(const float2*)&hb[s][2*k2];
        a0[s] += w0a*hv.x + w0b*hv.y;
        a1[s] += w1a*hv.x + w1b*hv.y;
      }
    }
    #pragma unroll
    for (int s = 0; s < 4; ++s) { gb[s][tid] = a0[s]; gb[s][tid+256] = a1[s]; }
    __syncthreads();

    #pragma unroll
    for (int r = 0; r < 2; ++r) {
      int s = r*2 + (tid >> 7);
      int u = tid & 127;
      float ig = sigmoidf_(gb[s][u]);
      float fg = sigmoidf_(gb[s][HIDN + u]);
      float gg = tanhf(gb[s][2*HIDN + u]);
      float og = sigmoidf_(gb[s][3*HIDN + u]);
      float cc = fg * cb[s][u] + ig * gg;
      float hh = og * tanhf(cc);
      cb[s][u] = cc;
      hb[s][u] = hh;
      enc_s[t][s][u] = hh;
    }
    __syncthreads();
  }

  // ----------------- decoder + head -----------------
  // decoder initial (h,c) = encoder final (h,c): already in hb/cb
  for (int t = 0; t < 32; ++t) {
    float a0[4] = {bd0, bd0, bd0, bd0};
    float a1[4] = {bd1, bd1, bd1, bd1};
    #pragma unroll 8
    for (int k2 = 0; k2 < 64; ++k2) {          // x = enc[t] (in=128)
      uint32_t u0 = pWih_d[k2*512 + tid];
      uint32_t u1 = pWih_d[k2*512 + tid + 256];
      float w0a = bf_lo(u0), w0b = bf_hi(u0);
      float w1a = bf_lo(u1), w1b = bf_hi(u1);
      #pragma unroll
      for (int s = 0; s < 4; ++s) {
        float2 xv = *(const float2*)&enc_s[t][s][2*k2];
        a0[s] += w0a*xv.x + w0b*xv.y;
        a1[s] += w1a*xv.x + w1b*xv.y;
      }
    }
    #pragma unroll 8
    for (int k2 = 0; k2 < 64; ++k2) {          // h contribution
      uint32_t u0 = pWhh_d[k2*512 + tid];
      uint32_t u1 = pWhh_d[k2*512 + tid + 256];
      float w0a = bf_lo(u0), w0b = bf_hi(u0);
      float w1a = bf_lo(u1), w1b = bf_hi(u1);
      #pragma unroll
      for (int s = 0; s < 4; ++s) {
        float2 hv = *(const float2*)&hb[s][2*k2];
        a0[s] += w0a*hv.x + w0b*hv.y;
        a1[s] += w1a*hv.x + w1b*hv.y;
      }
    }
    #pragma unroll
    for (int s = 0; s < 4; ++s) { gb[s][tid] = a0[s]; gb[s][tid+256] = a1[s]; }
    __syncthreads();

    #pragma unroll
    for (int r = 0; r < 2; ++r) {
      int s = r*2 + (tid >> 7);
      int u = tid & 127;
      float ig = sigmoidf_(gb[s][u]);
      float fg = sigmoidf_(gb[s][HIDN + u]);
      float gg = tanhf(gb[s][2*HIDN + u]);
      float og = sigmoidf_(gb[s][3*HIDN + u]);
      float cc = fg * cb[s][u] + ig * gg;
      float hh = og * tanhf(cc);
      cb[s][u] = cc;
      hb[s][u] = hh;
    }
    __syncthreads();

    // head: hid = relu(h @ W1.T + b1)
    {
      int s = tid >> 6, j = tid & 63;
      float acc = b1[j];
      #pragma unroll 8
      for (int u = 0; u < HIDN; ++u)
        acc += W1T[u*64 + j] * hb[s][u];
      hid[s][j] = fmaxf(acc, 0.0f);
    }
    __syncthreads();
    if (tid < 8) {
      int s = tid >> 1, e = tid & 1;
      float acc = b2[e];
      #pragma unroll
      for (int j = 0; j < 64; ++j)
        acc += W2[e*64 + j] * hid[s][j];
      out_kp[((bn0 + s)*32 + t)*2 + e] = acc;
    }
    __syncthreads();
  }
}

// ---------------------------------------------------------------------------
// Launch
// ---------------------------------------------------------------------------
extern "C" void kernel_launch(void* const* d_in, const int* in_sizes, int n_in,
                              void* d_out, int out_size, void* d_ws, size_t ws_size,
                              hipStream_t stream) {
  const float* x          = (const float*)d_in[0];
  const float* mask_point = (const float*)d_in[1];
  const int*   point_mask = (const int*)d_in[2];
  // d_in[3] = conv1_w (consumed by prep)
  const float* conv1_b    = (const float*)d_in[4];
  // d_in[5] = conv2_w (consumed by prep)
  const float* conv2_b    = (const float*)d_in[6];
  const float* Wih_e      = (const float*)d_in[7];
  const float* Whh_e      = (const float*)d_in[8];
  const float* bih_e      = (const float*)d_in[9];
  const float* bhh_e      = (const float*)d_in[10];
  const float* Wih_d      = (const float*)d_in[11];
  const float* Whh_d      = (const float*)d_in[12];
  const float* bih_d      = (const float*)d_in[13];
  const float* bhh_d      = (const float*)d_in[14];
  const float* W1         = (const float*)d_in[15];
  const float* b1         = (const float*)d_in[16];
  const float* W2         = (const float*)d_in[17];
  const float* b2         = (const float*)d_in[18];
  const float* conv1_w    = (const float*)d_in[3];
  const float* conv2_w    = (const float*)d_in[5];

  float* out = (float*)d_out;
  char*  ws  = (char*)d_ws;

  prep_kernel<<<(PREP_TOTAL + 255)/256, 256, 0, stream>>>(
      Wih_e, Whh_e, bih_e, bhh_e, Wih_d, Whh_d, bih_d, bhh_d,
      conv1_w, conv2_w, ws);

  points_kernel<<<64, 256, 0, stream>>>(
      mask_point, out + 32768, (int*)(ws + OFF_FLAT));

  conv_gather_kernel<<<512, 256, 0, stream>>>(
      x, point_mask, conv1_b, conv2_b,
      ws, (float*)(ws + OFF_DOTS), (const int*)(ws + OFF_FLAT));

  lstm_head_kernel<<<128, 256, 0, stream>>>(
      ws, W1, b1, W2, b2, out);
}

// Round 2
// 188.810 us; speedup vs baseline: 4.5655x; 4.5655x over previous
//
#include <hip/hip_runtime.h>
#include <stdint.h>

// ---------------------------------------------------------------------------
// Problem constants
// ---------------------------------------------------------------------------
#define NSEQ 512        // B*N
#define HIDN 128

// ws byte offsets
#define OFF_PWIH_E 0
#define OFF_PWHH_E (OFF_PWIH_E + 32*512*4)      //  65536
#define OFF_PWIH_D (OFF_PWHH_E + 64*512*4)      // 196608
#define OFF_PWHH_D (OFF_PWIH_D + 64*512*4)      // 327680
#define OFF_BIAS_E (OFF_PWHH_D + 64*512*4)      // 458752
#define OFF_BIAS_D (OFF_BIAS_E + 512*4)         // 460800
#define OFF_W1P    (OFF_BIAS_D + 512*4)         // 462848  conv w1 f16 pairs [288][64]
#define OFF_W2P    (OFF_W1P + 288*64*4)         // 536576  conv w2 f16 pairs [32][64]
#define OFF_FLAT   (OFF_W2P + 32*64*4)          // 544768  [16384] int
#define OFF_W1H    (OFF_FLAT + 16384*4)         // 610304  head W1 f16 pairs [64][64]
#define OFF_DOTS   (1024*1024)                  // [32][512][64] f16 = 2 MB

typedef _Float16 h2f __attribute__((ext_vector_type(2)));

static __device__ __forceinline__ h2f u2h(uint32_t u) {
  union { uint32_t u; h2f h; } v; v.u = u; return v.h;
}

#if __has_builtin(__builtin_amdgcn_fdot2)
static __device__ __forceinline__ float fdot2_(uint32_t a, uint32_t b, float c) {
  return __builtin_amdgcn_fdot2(u2h(a), u2h(b), c, false);
}
#else
static __device__ __forceinline__ float fdot2_(uint32_t a, uint32_t b, float c) {
  h2f x = u2h(a), y = u2h(b);
  return c + (float)x.x * (float)y.x + (float)x.y * (float)y.y;
}
#endif

static __device__ __forceinline__ uint32_t packh(float a, float b) {
  union { _Float16 h[2]; uint32_t u; } v;
  v.h[0] = (_Float16)a; v.h[1] = (_Float16)b; return v.u;
}
static __device__ __forceinline__ float sig_(float x) {
  return 1.0f / (1.0f + __expf(-x));
}
static __device__ __forceinline__ float tanh_(float x) {
  return 1.0f - 2.0f / (1.0f + __expf(2.0f * x));
}

// ---------------------------------------------------------------------------
// Kernel 0: weight prep (transpose + f16 pack + bias sums)
// ---------------------------------------------------------------------------
__global__ __launch_bounds__(256) void prep_kernel(
    const float* Wih_e, const float* Whh_e,
    const float* bih_e, const float* bhh_e,
    const float* Wih_d, const float* Whh_d,
    const float* bih_d, const float* bhh_d,
    const float* w1, const float* w2, const float* W1, char* ws) {
  uint32_t* pWih_e = (uint32_t*)(ws + OFF_PWIH_E);
  uint32_t* pWhh_e = (uint32_t*)(ws + OFF_PWHH_E);
  uint32_t* pWih_d = (uint32_t*)(ws + OFF_PWIH_D);
  uint32_t* pWhh_d = (uint32_t*)(ws + OFF_PWHH_D);
  float*    bias_e = (float*)(ws + OFF_BIAS_E);
  float*    bias_d = (float*)(ws + OFF_BIAS_D);
  uint32_t* w1p    = (uint32_t*)(ws + OFF_W1P);
  uint32_t* w2p    = (uint32_t*)(ws + OFF_W2P);
  uint32_t* W1h    = (uint32_t*)(ws + OFF_W1H);

  int idx = blockIdx.x * 256 + threadIdx.x;
  if (idx < 32*512) {                             // pWih_e [k2][g], in=64
    int k2 = idx >> 9, g = idx & 511;
    pWih_e[idx] = packh(Wih_e[g*64 + 2*k2], Wih_e[g*64 + 2*k2 + 1]);
    return;
  }
  idx -= 32*512;
  if (idx < 64*512) {                             // pWhh_e, in=128
    int k2 = idx >> 9, g = idx & 511;
    pWhh_e[idx] = packh(Whh_e[g*128 + 2*k2], Whh_e[g*128 + 2*k2 + 1]);
    return;
  }
  idx -= 64*512;
  if (idx < 64*512) {                             // pWih_d, in=128
    int k2 = idx >> 9, g = idx & 511;
    pWih_d[idx] = packh(Wih_d[g*128 + 2*k2], Wih_d[g*128 + 2*k2 + 1]);
    return;
  }
  idx -= 64*512;
  if (idx < 64*512) {                             // pWhh_d, in=128
    int k2 = idx >> 9, g = idx & 511;
    pWhh_d[idx] = packh(Whh_d[g*128 + 2*k2], Whh_d[g*128 + 2*k2 + 1]);
    return;
  }
  idx -= 64*512;
  if (idx < 512) { bias_e[idx] = bih_e[idx] + bhh_e[idx]; return; }
  idx -= 512;
  if (idx < 512) { bias_d[idx] = bih_d[idx] + bhh_d[idx]; return; }
  idx -= 512;
  if (idx < 288*64) {                             // conv w1 pairs [i2][c]
    int i2 = idx >> 6, c = idx & 63;
    w1p[idx] = packh(w1[c*576 + 2*i2], w1[c*576 + 2*i2 + 1]);
    return;
  }
  idx -= 288*64;
  if (idx < 32*64) {                              // conv w2 pairs [c2][d]
    int c2 = idx >> 6, d = idx & 63;
    w2p[idx] = packh(w2[d*64 + 2*c2], w2[d*64 + 2*c2 + 1]);
    return;
  }
  idx -= 32*64;
  if (idx < 64*64) {                              // head W1 pairs [k2][j]
    int k2 = idx >> 6, j = idx & 63;
    W1h[idx] = packh(W1[j*128 + 2*k2], W1[j*128 + 2*k2 + 1]);
    return;
  }
}
#define PREP_TOTAL (32*512 + 3*64*512 + 512 + 512 + 288*64 + 32*64 + 64*64)

// ---------------------------------------------------------------------------
// Kernel 1: point math -> gt (output 1) + flat indices
// ---------------------------------------------------------------------------
__global__ __launch_bounds__(256) void points_kernel(
    const float* mask_point, float* out_gt, int* flat) {
  int p = blockIdx.x * 256 + threadIdx.x;
  if (p >= 16384) return;
  float mx = mask_point[p*2 + 0];
  float my = mask_point[p*2 + 1];
  float fx = fminf(mx * 0.25f, 127.0f);
  float fy = fminf(my * 0.25f, 127.0f);
  out_gt[p*2 + 0] = fx * 4.0f;
  out_gt[p*2 + 1] = fy * 4.0f;
  flat[p] = (int)(__fmaf_rn(fy, 128.0f, fx));   // fy*128 exact -> fma == mul+add
}

// ---------------------------------------------------------------------------
// Kernel 2: fused gathered conv (3x3 -> ReLU -> 1x1) at points, 4 pts/group
// ---------------------------------------------------------------------------
__global__ __launch_bounds__(256, 2) void conv_gather_kernel(
    const float* x, const int* point_mask,
    const float* conv1_b, const float* conv2_b,
    const char* ws_ro, _Float16* dots_h, const int* flat) {
  __shared__ uint32_t w1s[288*64];    // 73728 B
  __shared__ uint32_t patch2[4*288];  //  4608 B (f16 pairs, [slot][288])
  __shared__ uint32_t tl2[4*32];      //   512 B (f16 pairs, [slot][32])

  const uint32_t* w1p = (const uint32_t*)(ws_ro + OFF_W1P);
  const uint32_t* w2p = (const uint32_t*)(ws_ro + OFF_W2P);
  int tid = threadIdx.x;
  for (int i = tid; i < 288*64; i += 256) w1s[i] = w1p[i];

  int q = tid >> 6, c = tid & 63;
  float c1b = conv1_b[c], c2b = conv2_b[c];

  for (int g = 0; g < 8; ++g) {
    int p0 = blockIdx.x * 32 + g * 4;
    __syncthreads();                       // patch2 safe to overwrite (+ w1s ready, g==0)
    #pragma unroll
    for (int r = 0; r < 9; ++r) {          // 2304 = 4 pts x 576 halves
      int l = tid + 256 * r;
      int slot = l / 576;
      int within = l - slot * 576;
      int cp = within / 9;
      int tap = within - cp * 9;
      int p = p0 + slot;
      int fl = flat[p];
      int hh = fl >> 7, ww = fl & 127;
      int b = p >> 10;
      int yy = hh + tap / 3 - 1, xx = ww + tap % 3 - 1;
      float v = 0.0f;
      if (yy >= 0 && yy < 128 && xx >= 0 && xx < 128)
        v = x[((b*64 + cp)*128 + yy)*128 + xx];
      ((_Float16*)patch2)[l] = (_Float16)v;
    }
    __syncthreads();

    // conv1: thread (q,c) = full 576-input dot for channel c of point q
    float a0 = c1b, a1 = 0.f, a2 = 0.f, a3 = 0.f;
    #pragma unroll 4
    for (int i2 = 0; i2 < 288; i2 += 4) {
      a0 = fdot2_(w1s[(i2+0)*64 + c], patch2[q*288 + i2+0], a0);
      a1 = fdot2_(w1s[(i2+1)*64 + c], patch2[q*288 + i2+1], a1);
      a2 = fdot2_(w1s[(i2+2)*64 + c], patch2[q*288 + i2+2], a2);
      a3 = fdot2_(w1s[(i2+3)*64 + c], patch2[q*288 + i2+3], a3);
    }
    float t1 = fmaxf((a0 + a1) + (a2 + a3), 0.0f);
    ((_Float16*)tl2)[q*64 + c] = (_Float16)t1;
    // tl2[q] written and read by the same wave -> no barrier needed

    // conv2: thread (q,d=c)
    float acc2 = c2b;
    #pragma unroll
    for (int c2 = 0; c2 < 32; ++c2)
      acc2 = fdot2_(w2p[c2*64 + c], tl2[q*32 + c2], acc2);
    int p = p0 + q;
    acc2 *= (float)point_mask[p];
    int k = p & 31, bn = p >> 5;
    dots_h[(k*NSEQ + bn)*64 + c] = (_Float16)acc2;   // time-major [k][bn][d]
  }
}

// ---------------------------------------------------------------------------
// Kernel 3: encoder LSTM + decoder LSTM + batched MLP head.
// 256 blocks x 512 threads; 2 sequences/block, 1 gate/thread,
// weight rows in VGPRs (f16 pairs), fdot2 inner products.
// ---------------------------------------------------------------------------
__global__ __launch_bounds__(512, 2) void lstm_head_kernel(
    const char* ws_ro, const float* b1, const float* W2, const float* b2,
    float* out_kp) {
  const uint32_t* pWih_e = (const uint32_t*)(ws_ro + OFF_PWIH_E);
  const uint32_t* pWhh_e = (const uint32_t*)(ws_ro + OFF_PWHH_E);
  const uint32_t* pWih_d = (const uint32_t*)(ws_ro + OFF_PWIH_D);
  const uint32_t* pWhh_d = (const uint32_t*)(ws_ro + OFF_PWHH_D);
  const float*    bias_e = (const float*)(ws_ro + OFF_BIAS_E);
  const float*    bias_d = (const float*)(ws_ro + OFF_BIAS_D);
  const uint32_t* dots_u = (const uint32_t*)(ws_ro + OFF_DOTS);
  const uint32_t* W1h    = (const uint32_t*)(ws_ro + OFF_W1H);

  __shared__ uint32_t xall2[2][32][32];   //  8 KB (x as f16 pairs)
  __shared__ uint32_t enc2[2][32][64];    // 16 KB (enc h as f16 pairs)
  __shared__ uint32_t dech2[2][32][64];   // 16 KB (dec h as f16 pairs)
  __shared__ uint32_t hb2[2][64];         // 512 B (current h, f16 pairs)
  __shared__ float    gb[2][512];         //  4 KB (gates)
  __shared__ float    hidf[64][65];       // 16.6 KB (head hidden, padded)

  int tid = threadIdx.x;
  int bn0 = blockIdx.x * 2;

  uint32_t wih[64], whh[64];
  #pragma unroll
  for (int k = 0; k < 32; ++k) wih[k] = pWih_e[k*512 + tid];
  #pragma unroll
  for (int k = 0; k < 64; ++k) whh[k] = pWhh_e[k*512 + tid];
  float bg = bias_e[tid];

  #pragma unroll
  for (int r = 0; r < 4; ++r) {           // stage all x for both seqs
    int i = tid + 512 * r;
    int s = i >> 10, rem = i & 1023, t = rem >> 5, k2 = rem & 31;
    xall2[s][t][k2] = dots_u[(t*NSEQ + bn0 + s)*32 + k2];
  }
  if (tid < 128) hb2[tid >> 6][tid & 63] = 0u;
  float c_reg = 0.0f;
  __syncthreads();

  // ----------------- encoder -----------------
  for (int t = 0; t < 32; ++t) {
    float a0 = bg, a1 = bg, p0 = 0.f, p1 = 0.f;
    #pragma unroll
    for (int k = 0; k < 32; k += 2) {
      a0 = fdot2_(wih[k],   xall2[0][t][k],   a0);
      a1 = fdot2_(wih[k],   xall2[1][t][k],   a1);
      p0 = fdot2_(wih[k+1], xall2[0][t][k+1], p0);
      p1 = fdot2_(wih[k+1], xall2[1][t][k+1], p1);
    }
    #pragma unroll
    for (int k = 0; k < 64; k += 2) {
      a0 = fdot2_(whh[k],   hb2[0][k],   a0);
      a1 = fdot2_(whh[k],   hb2[1][k],   a1);
      p0 = fdot2_(whh[k+1], hb2[0][k+1], p0);
      p1 = fdot2_(whh[k+1], hb2[1][k+1], p1);
    }
    gb[0][tid] = a0 + p0;
    gb[1][tid] = a1 + p1;
    __syncthreads();
    if (tid < 256) {
      int s = tid >> 7, u = tid & 127;
      float ig = sig_(gb[s][u]);
      float fg = sig_(gb[s][128 + u]);
      float gg = tanh_(gb[s][256 + u]);
      float og = sig_(gb[s][384 + u]);
      c_reg = fg * c_reg + ig * gg;
      float hh = og * tanh_(c_reg);
      _Float16 hv = (_Float16)hh;
      ((_Float16*)&hb2[s][0])[u] = hv;
      ((_Float16*)&enc2[s][t][0])[u] = hv;
    }
    __syncthreads();
  }

  // ----------------- decoder -----------------
  #pragma unroll
  for (int k = 0; k < 64; ++k) {
    wih[k] = pWih_d[k*512 + tid];
    whh[k] = pWhh_d[k*512 + tid];
  }
  bg = bias_d[tid];

  for (int t = 0; t < 32; ++t) {
    float a0 = bg, a1 = bg, p0 = 0.f, p1 = 0.f;
    #pragma unroll
    for (int k = 0; k < 64; k += 2) {
      a0 = fdot2_(wih[k],   enc2[0][t][k],   a0);
      a1 = fdot2_(wih[k],   enc2[1][t][k],   a1);
      p0 = fdot2_(wih[k+1], enc2[0][t][k+1], p0);
      p1 = fdot2_(wih[k+1], enc2[1][t][k+1], p1);
    }
    #pragma unroll
    for (int k = 0; k < 64; k += 2) {
      a0 = fdot2_(whh[k],   hb2[0][k],   a0);
      a1 = fdot2_(whh[k],   hb2[1][k],   a1);
      p0 = fdot2_(whh[k+1], hb2[0][k+1], p0);
      p1 = fdot2_(whh[k+1], hb2[1][k+1], p1);
    }
    gb[0][tid] = a0 + p0;
    gb[1][tid] = a1 + p1;
    __syncthreads();
    if (tid < 256) {
      int s = tid >> 7, u = tid & 127;
      float ig = sig_(gb[s][u]);
      float fg = sig_(gb[s][128 + u]);
      float gg = tanh_(gb[s][256 + u]);
      float og = sig_(gb[s][384 + u]);
      c_reg = fg * c_reg + ig * gg;
      float hh = og * tanh_(c_reg);
      _Float16 hv = (_Float16)hh;
      ((_Float16*)&hb2[s][0])[u] = hv;
      ((_Float16*)&dech2[s][t][0])[u] = hv;
    }
    __syncthreads();
  }

  // ----------------- head: hid = relu(dec @ W1.T + b1); y = hid @ W2.T + b2
  {
    int j = tid & 63, w = tid >> 6;       // wave handles st = w + 8*m
    float acc[8];
    #pragma unroll
    for (int m = 0; m < 8; ++m) acc[m] = b1[j];
    #pragma unroll 8
    for (int k = 0; k < 64; ++k) {
      uint32_t wv = W1h[k*64 + j];
      #pragma unroll
      for (int m = 0; m < 8; ++m) {
        int st = w + 8*m;
        acc[m] = fdot2_(wv, dech2[st >> 5][st & 31][k], acc[m]);
      }
    }
    #pragma unroll
    for (int m = 0; m < 8; ++m) {
      int st = w + 8*m;
      hidf[st][j] = fmaxf(acc[m], 0.0f);
    }
  }
  __syncthreads();
  if (tid < 128) {
    int st = tid >> 1, e = tid & 1;
    float acc = b2[e];
    #pragma unroll 16
    for (int j = 0; j < 64; ++j) acc += W2[e*64 + j] * hidf[st][j];
    int s = st >> 5, t = st & 31;
    out_kp[((bn0 + s)*32 + t)*2 + e] = acc;
  }
}

// ---------------------------------------------------------------------------
// Launch
// ---------------------------------------------------------------------------
extern "C" void kernel_launch(void* const* d_in, const int* in_sizes, int n_in,
                              void* d_out, int out_size, void* d_ws, size_t ws_size,
                              hipStream_t stream) {
  const float* x          = (const float*)d_in[0];
  const float* mask_point = (const float*)d_in[1];
  const int*   point_mask = (const int*)d_in[2];
  const float* conv1_w    = (const float*)d_in[3];
  const float* conv1_b    = (const float*)d_in[4];
  const float* conv2_w    = (const float*)d_in[5];
  const float* conv2_b    = (const float*)d_in[6];
  const float* Wih_e      = (const float*)d_in[7];
  const float* Whh_e      = (const float*)d_in[8];
  const float* bih_e      = (const float*)d_in[9];
  const float* bhh_e      = (const float*)d_in[10];
  const float* Wih_d      = (const float*)d_in[11];
  const float* Whh_d      = (const float*)d_in[12];
  const float* bih_d      = (const float*)d_in[13];
  const float* bhh_d      = (const float*)d_in[14];
  const float* W1         = (const float*)d_in[15];
  const float* b1         = (const float*)d_in[16];
  const float* W2         = (const float*)d_in[17];
  const float* b2         = (const float*)d_in[18];

  float* out = (float*)d_out;
  char*  ws  = (char*)d_ws;

  prep_kernel<<<(PREP_TOTAL + 255)/256, 256, 0, stream>>>(
      Wih_e, Whh_e, bih_e, bhh_e, Wih_d, Whh_d, bih_d, bhh_d,
      conv1_w, conv2_w, W1, ws);

  points_kernel<<<64, 256, 0, stream>>>(
      mask_point, out + 32768, (int*)(ws + OFF_FLAT));

  conv_gather_kernel<<<512, 256, 0, stream>>>(
      x, point_mask, conv1_b, conv2_b,
      ws, (_Float16*)(ws + OFF_DOTS), (const int*)(ws + OFF_FLAT));

  lstm_head_kernel<<<256, 512, 0, stream>>>(
      ws, b1, W2, b2, out);
}

// Round 3
// 182.902 us; speedup vs baseline: 4.7130x; 1.0323x over previous
//
#include <hip/hip_runtime.h>
#include <stdint.h>

// ---------------------------------------------------------------------------
// Problem constants
// ---------------------------------------------------------------------------
#define NSEQ 512        // B*N
#define HIDN 128

// ws byte offsets
#define OFF_PWIH_E 0
#define OFF_PWHH_E (OFF_PWIH_E + 32*512*4)      //  65536
#define OFF_PWIH_D (OFF_PWHH_E + 64*512*4)      // 196608
#define OFF_PWHH_D (OFF_PWIH_D + 64*512*4)      // 327680
#define OFF_BIAS_E (OFF_PWHH_D + 64*512*4)      // 458752
#define OFF_BIAS_D (OFF_BIAS_E + 512*4)         // 460800
#define OFF_W1P    (OFF_BIAS_D + 512*4)         // 462848  conv w1 f16 pairs [288][64]
#define OFF_W2P    (OFF_W1P + 288*64*4)         // 536576  conv w2 f16 pairs [32][64]
#define OFF_FLAT   (OFF_W2P + 32*64*4)          // 544768  [16384] int
#define OFF_W1H    (OFF_FLAT + 16384*4)         // 610304  head W1 f16 pairs [64][64]
#define OFF_DOTS   (1024*1024)                  // [32][512][64] f16 = 2 MB
#define OFF_XT     (4*1024*1024)                // xT [16][128][128][64] f16 = 33.5 MB
#define WS_NEED_XT ((size_t)(4*1024*1024) + (size_t)16*128*128*64*2 + 1024)

typedef _Float16 h2f __attribute__((ext_vector_type(2)));

static __device__ __forceinline__ h2f u2h(uint32_t u) {
  union { uint32_t u; h2f h; } v; v.u = u; return v.h;
}

#if __has_builtin(__builtin_amdgcn_fdot2)
static __device__ __forceinline__ float fdot2_(uint32_t a, uint32_t b, float c) {
  return __builtin_amdgcn_fdot2(u2h(a), u2h(b), c, false);
}
#else
static __device__ __forceinline__ float fdot2_(uint32_t a, uint32_t b, float c) {
  h2f x = u2h(a), y = u2h(b);
  return c + (float)x.x * (float)y.x + (float)x.y * (float)y.y;
}
#endif

static __device__ __forceinline__ uint32_t packh(float a, float b) {
  union { _Float16 h[2]; uint32_t u; } v;
  v.h[0] = (_Float16)a; v.h[1] = (_Float16)b; return v.u;
}
static __device__ __forceinline__ float sig_(float x) {
  return 1.0f / (1.0f + __expf(-x));
}
static __device__ __forceinline__ float tanh_(float x) {
  return 1.0f - 2.0f / (1.0f + __expf(2.0f * x));
}

// ---------------------------------------------------------------------------
// Kernel 0: weight prep (transpose + f16 pack + bias sums)
// w1_order: 0 = pairs along (cin*9+tap) flat index; 1 = pairs along (tap*64+cin)
// ---------------------------------------------------------------------------
__global__ __launch_bounds__(256) void prep_kernel(
    const float* Wih_e, const float* Whh_e,
    const float* bih_e, const float* bhh_e,
    const float* Wih_d, const float* Whh_d,
    const float* bih_d, const float* bhh_d,
    const float* w1, const float* w2, const float* W1, char* ws, int w1_order) {
  uint32_t* pWih_e = (uint32_t*)(ws + OFF_PWIH_E);
  uint32_t* pWhh_e = (uint32_t*)(ws + OFF_PWHH_E);
  uint32_t* pWih_d = (uint32_t*)(ws + OFF_PWIH_D);
  uint32_t* pWhh_d = (uint32_t*)(ws + OFF_PWHH_D);
  float*    bias_e = (float*)(ws + OFF_BIAS_E);
  float*    bias_d = (float*)(ws + OFF_BIAS_D);
  uint32_t* w1p    = (uint32_t*)(ws + OFF_W1P);
  uint32_t* w2p    = (uint32_t*)(ws + OFF_W2P);
  uint32_t* W1h    = (uint32_t*)(ws + OFF_W1H);

  int idx = blockIdx.x * 256 + threadIdx.x;
  if (idx < 32*512) {                             // pWih_e [k2][g], in=64
    int k2 = idx >> 9, g = idx & 511;
    pWih_e[idx] = packh(Wih_e[g*64 + 2*k2], Wih_e[g*64 + 2*k2 + 1]);
    return;
  }
  idx -= 32*512;
  if (idx < 64*512) {                             // pWhh_e, in=128
    int k2 = idx >> 9, g = idx & 511;
    pWhh_e[idx] = packh(Whh_e[g*128 + 2*k2], Whh_e[g*128 + 2*k2 + 1]);
    return;
  }
  idx -= 64*512;
  if (idx < 64*512) {                             // pWih_d, in=128
    int k2 = idx >> 9, g = idx & 511;
    pWih_d[idx] = packh(Wih_d[g*128 + 2*k2], Wih_d[g*128 + 2*k2 + 1]);
    return;
  }
  idx -= 64*512;
  if (idx < 64*512) {                             // pWhh_d, in=128
    int k2 = idx >> 9, g = idx & 511;
    pWhh_d[idx] = packh(Whh_d[g*128 + 2*k2], Whh_d[g*128 + 2*k2 + 1]);
    return;
  }
  idx -= 64*512;
  if (idx < 512) { bias_e[idx] = bih_e[idx] + bhh_e[idx]; return; }
  idx -= 512;
  if (idx < 512) { bias_d[idx] = bih_d[idx] + bhh_d[idx]; return; }
  idx -= 512;
  if (idx < 288*64) {                             // conv w1 pairs [i2][c]
    int i2 = idx >> 6, c = idx & 63;
    if (w1_order) {
      int tap = i2 >> 5, cin = (i2 & 31) * 2;     // i2 = tap*32 + c2
      w1p[idx] = packh(w1[c*576 + cin*9 + tap], w1[c*576 + (cin+1)*9 + tap]);
    } else {
      w1p[idx] = packh(w1[c*576 + 2*i2], w1[c*576 + 2*i2 + 1]);
    }
    return;
  }
  idx -= 288*64;
  if (idx < 32*64) {                              // conv w2 pairs [c2][d]
    int c2 = idx >> 6, d = idx & 63;
    w2p[idx] = packh(w2[d*64 + 2*c2], w2[d*64 + 2*c2 + 1]);
    return;
  }
  idx -= 32*64;
  if (idx < 64*64) {                              // head W1 pairs [k2][j]
    int k2 = idx >> 6, j = idx & 63;
    W1h[idx] = packh(W1[j*128 + 2*k2], W1[j*128 + 2*k2 + 1]);
    return;
  }
}
#define PREP_TOTAL (32*512 + 3*64*512 + 512 + 512 + 288*64 + 32*64 + 64*64)

// ---------------------------------------------------------------------------
// Kernel 1: point math -> gt (output 1) + flat indices
// ---------------------------------------------------------------------------
__global__ __launch_bounds__(256) void points_kernel(
    const float* mask_point, float* out_gt, int* flat) {
  int p = blockIdx.x * 256 + threadIdx.x;
  if (p >= 16384) return;
  float mx = mask_point[p*2 + 0];
  float my = mask_point[p*2 + 1];
  float fx = fminf(mx * 0.25f, 127.0f);
  float fy = fminf(my * 0.25f, 127.0f);
  out_gt[p*2 + 0] = fx * 4.0f;
  out_gt[p*2 + 1] = fy * 4.0f;
  flat[p] = (int)(__fmaf_rn(fy, 128.0f, fx));   // fy*128 exact -> fma == mul+add
}

// ---------------------------------------------------------------------------
// Kernel T: x [16][64][128][128] f32 -> xT [16][128][128][64] f16 (NHWC)
// Tile: 1 batch x 8 rows x 32 cols, all 64 channels, via LDS.
// ---------------------------------------------------------------------------
__global__ __launch_bounds__(256, 2) void transpose_kernel(
    const float* x, uint32_t* xT32) {
  __shared__ float lds[64][257];
  int bid = blockIdx.x;           // 1024 = 16 b x 16 yt x 4 xt
  int xt = bid & 3, yt = (bid >> 2) & 15, b = bid >> 6;
  int x0 = xt * 32, y0 = yt * 8;
  int tx = threadIdx.x & 31, ty = threadIdx.x >> 5;
  #pragma unroll 8
  for (int c = 0; c < 64; ++c)
    lds[c][ty*32 + tx] = x[((b*64 + c)*128 + (y0 + ty))*128 + (x0 + tx)];
  __syncthreads();
  #pragma unroll 8
  for (int r = 0; r < 32; ++r) {
    int i = threadIdx.x + 256*r;    // i = pos*32 + c2
    int c2 = i & 31, pos = i >> 5;
    int yy = pos >> 5, xx = pos & 31;
    float lo = lds[2*c2][yy*32 + xx], hi = lds[2*c2 + 1][yy*32 + xx];
    xT32[((b*128 + y0 + yy)*128 + (x0 + xx))*32 + c2] = packh(lo, hi);
  }
}

// ---------------------------------------------------------------------------
// Kernel 2: fused gathered conv (3x3 -> ReLU -> 1x1) at points, 4 pts/group
// MODE 1: patches from NHWC-f16 xT (coalesced). MODE 0: from NCHW f32 x.
// w1 staged in LDS transposed [c][i2] (pad 291) for ds_read_b128 on both streams.
// ---------------------------------------------------------------------------
template <int MODE>
__global__ __launch_bounds__(256, 2) void conv_gather_kernel(
    const float* x, const uint32_t* xT32, const int* point_mask,
    const float* conv1_b, const float* conv2_b,
    const char* ws_ro, _Float16* dots_h, const int* flat) {
  __shared__ uint32_t w1s[64*291];    // 74496 B
  __shared__ uint32_t patch2[4*288];  //  4608 B (f16 pairs per point slot)
  __shared__ uint32_t tl2[4*32];      //   512 B

  const uint32_t* w1p = (const uint32_t*)(ws_ro + OFF_W1P);
  const uint32_t* w2p = (const uint32_t*)(ws_ro + OFF_W2P);
  int tid = threadIdx.x;
  for (int i = tid; i < 288*64; i += 256) {
    int i2 = i >> 6, cc = i & 63;
    w1s[cc*291 + i2] = w1p[i];
  }

  int q = tid >> 6, c = tid & 63;
  float c1b = conv1_b[c], c2b = conv2_b[c];

  for (int g = 0; g < 8; ++g) {
    int p0 = blockIdx.x * 32 + g * 4;
    __syncthreads();                 // patch2 reusable (+ w1s ready at g==0)
    if (MODE == 1) {
      #pragma unroll
      for (int r = 0; r < 5; ++r) {  // 1152 u32 = 4 pts x 288
        int u = tid + 256*r;
        if (u < 1152) {
          int slot = u / 288, w = u - slot*288;
          int tap = w >> 5, c2i = w & 31;
          int p = p0 + slot;
          int fl = flat[p];
          int hh = fl >> 7, ww = fl & 127;
          int b = p >> 10;
          int dy = tap / 3, dx = tap - dy*3;
          int yy = hh + dy - 1, xx = ww + dx - 1;
          uint32_t v = 0u;
          if (yy >= 0 && yy < 128 && xx >= 0 && xx < 128)
            v = xT32[((b*128 + yy)*128 + xx)*32 + c2i];
          patch2[slot*288 + w] = v;
        }
      }
    } else {
      #pragma unroll
      for (int r = 0; r < 9; ++r) {  // 2304 halves = 4 pts x 576
        int l = tid + 256*r;
        int slot = l / 576;
        int within = l - slot*576;
        int cp = within / 9;
        int tap = within - cp*9;
        int p = p0 + slot;
        int fl = flat[p];
        int hh = fl >> 7, ww = fl & 127;
        int b = p >> 10;
        int yy = hh + tap/3 - 1, xx = ww + tap%3 - 1;
        float v = 0.0f;
        if (yy >= 0 && yy < 128 && xx >= 0 && xx < 128)
          v = x[((b*64 + cp)*128 + yy)*128 + xx];
        ((_Float16*)patch2)[l] = (_Float16)v;
      }
    }
    __syncthreads();

    // conv1: thread (q,c) = full 576-input dot for channel c of point q
    float a0 = c1b, a1 = 0.f, a2 = 0.f, a3 = 0.f;
    int cbase = c * 291, pbase = q * 288;
    #pragma unroll 4
    for (int i2 = 0; i2 < 288; i2 += 4) {
      a0 = fdot2_(w1s[cbase + i2+0], patch2[pbase + i2+0], a0);
      a1 = fdot2_(w1s[cbase + i2+1], patch2[pbase + i2+1], a1);
      a2 = fdot2_(w1s[cbase + i2+2], patch2[pbase + i2+2], a2);
      a3 = fdot2_(w1s[cbase + i2+3], patch2[pbase + i2+3], a3);
    }
    float t1 = fmaxf((a0 + a1) + (a2 + a3), 0.0f);
    ((_Float16*)tl2)[q*64 + c] = (_Float16)t1;
    // tl2[q] written and read by the same wave (q == tid>>6) -> no barrier

    float acc2 = c2b;
    #pragma unroll
    for (int c2i = 0; c2i < 32; ++c2i)
      acc2 = fdot2_(w2p[c2i*64 + c], tl2[q*32 + c2i], acc2);
    int p = p0 + q;
    acc2 *= (float)point_mask[p];
    int k = p & 31, bn = p >> 5;
    dots_h[(k*NSEQ + bn)*64 + c] = (_Float16)acc2;   // time-major [k][bn][d]
  }
}

// ---------------------------------------------------------------------------
// Kernel 3: encoder LSTM + decoder LSTM + batched MLP head.
// 256 blocks x 512 threads; 2 seqs/block, 1 gate/thread.
// Weights pinned in VGPRs via asm (launch_bounds(512,1) -> 256-reg budget).
// ---------------------------------------------------------------------------
__global__ __launch_bounds__(512, 1) void lstm_head_kernel(
    const char* ws_ro, const float* b1, const float* W2, const float* b2,
    float* out_kp) {
  const uint32_t* pWih_e = (const uint32_t*)(ws_ro + OFF_PWIH_E);
  const uint32_t* pWhh_e = (const uint32_t*)(ws_ro + OFF_PWHH_E);
  const uint32_t* pWih_d = (const uint32_t*)(ws_ro + OFF_PWIH_D);
  const uint32_t* pWhh_d = (const uint32_t*)(ws_ro + OFF_PWHH_D);
  const float*    bias_e = (const float*)(ws_ro + OFF_BIAS_E);
  const float*    bias_d = (const float*)(ws_ro + OFF_BIAS_D);
  const uint32_t* dots_u = (const uint32_t*)(ws_ro + OFF_DOTS);
  const uint32_t* W1h    = (const uint32_t*)(ws_ro + OFF_W1H);

  __shared__ uint32_t xall2[2][32][32];   //  8 KB
  __shared__ uint32_t enc2[2][32][64];    // 16 KB
  __shared__ uint32_t dech2[2][32][64];   // 16 KB
  __shared__ uint32_t hb2[2][64];         // 512 B
  __shared__ float    gb[2][512];         //  4 KB
  __shared__ float    hidf[64][65];       // 16.6 KB

  int tid = threadIdx.x;
  int bn0 = blockIdx.x * 2;

  uint32_t wih[64], whh[64];
  #pragma unroll
  for (int k = 0; k < 32; ++k) wih[k] = pWih_e[k*512 + tid];
  #pragma unroll
  for (int k = 0; k < 64; ++k) whh[k] = pWhh_e[k*512 + tid];
  #pragma unroll
  for (int k = 0; k < 32; ++k) asm volatile("" : "+v"(wih[k]));
  #pragma unroll
  for (int k = 0; k < 64; ++k) asm volatile("" : "+v"(whh[k]));
  float bg = bias_e[tid];

  #pragma unroll
  for (int r = 0; r < 4; ++r) {           // stage all x for both seqs
    int i = tid + 512 * r;
    int s = i >> 10, rem = i & 1023, t = rem >> 5, k2 = rem & 31;
    xall2[s][t][k2] = dots_u[(t*NSEQ + bn0 + s)*32 + k2];
  }
  if (tid < 128) hb2[tid >> 6][tid & 63] = 0u;
  float c_reg = 0.0f;
  __syncthreads();

  // ----------------- encoder -----------------
  for (int t = 0; t < 32; ++t) {
    float a0 = bg, a1 = bg, p0 = 0.f, p1 = 0.f;
    #pragma unroll
    for (int k = 0; k < 32; k += 2) {
      a0 = fdot2_(wih[k],   xall2[0][t][k],   a0);
      a1 = fdot2_(wih[k],   xall2[1][t][k],   a1);
      p0 = fdot2_(wih[k+1], xall2[0][t][k+1], p0);
      p1 = fdot2_(wih[k+1], xall2[1][t][k+1], p1);
    }
    #pragma unroll
    for (int k = 0; k < 64; k += 2) {
      a0 = fdot2_(whh[k],   hb2[0][k],   a0);
      a1 = fdot2_(whh[k],   hb2[1][k],   a1);
      p0 = fdot2_(whh[k+1], hb2[0][k+1], p0);
      p1 = fdot2_(whh[k+1], hb2[1][k+1], p1);
    }
    gb[0][tid] = a0 + p0;
    gb[1][tid] = a1 + p1;
    __syncthreads();
    if (tid < 256) {
      int s = tid >> 7, u = tid & 127;
      float ig = sig_(gb[s][u]);
      float fg = sig_(gb[s][128 + u]);
      float gg = tanh_(gb[s][256 + u]);
      float og = sig_(gb[s][384 + u]);
      c_reg = fg * c_reg + ig * gg;
      float hh = og * tanh_(c_reg);
      _Float16 hv = (_Float16)hh;
      ((_Float16*)&hb2[s][0])[u] = hv;
      ((_Float16*)&enc2[s][t][0])[u] = hv;
    }
    __syncthreads();
  }

  // ----------------- decoder -----------------
  #pragma unroll
  for (int k = 0; k < 64; ++k) {
    wih[k] = pWih_d[k*512 + tid];
    whh[k] = pWhh_d[k*512 + tid];
  }
  #pragma unroll
  for (int k = 0; k < 64; ++k) asm volatile("" : "+v"(wih[k]));
  #pragma unroll
  for (int k = 0; k < 64; ++k) asm volatile("" : "+v"(whh[k]));
  bg = bias_d[tid];

  for (int t = 0; t < 32; ++t) {
    float a0 = bg, a1 = bg, p0 = 0.f, p1 = 0.f;
    #pragma unroll
    for (int k = 0; k < 64; k += 2) {
      a0 = fdot2_(wih[k],   enc2[0][t][k],   a0);
      a1 = fdot2_(wih[k],   enc2[1][t][k],   a1);
      p0 = fdot2_(wih[k+1], enc2[0][t][k+1], p0);
      p1 = fdot2_(wih[k+1], enc2[1][t][k+1], p1);
    }
    #pragma unroll
    for (int k = 0; k < 64; k += 2) {
      a0 = fdot2_(whh[k],   hb2[0][k],   a0);
      a1 = fdot2_(whh[k],   hb2[1][k],   a1);
      p0 = fdot2_(whh[k+1], hb2[0][k+1], p0);
      p1 = fdot2_(whh[k+1], hb2[1][k+1], p1);
    }
    gb[0][tid] = a0 + p0;
    gb[1][tid] = a1 + p1;
    __syncthreads();
    if (tid < 256) {
      int s = tid >> 7, u = tid & 127;
      float ig = sig_(gb[s][u]);
      float fg = sig_(gb[s][128 + u]);
      float gg = tanh_(gb[s][256 + u]);
      float og = sig_(gb[s][384 + u]);
      c_reg = fg * c_reg + ig * gg;
      float hh = og * tanh_(c_reg);
      _Float16 hv = (_Float16)hh;
      ((_Float16*)&hb2[s][0])[u] = hv;
      ((_Float16*)&dech2[s][t][0])[u] = hv;
    }
    __syncthreads();
  }

  // ----------------- head -----------------
  {
    int j = tid & 63, w = tid >> 6;
    float acc[8];
    #pragma unroll
    for (int m = 0; m < 8; ++m) acc[m] = b1[j];
    #pragma unroll 8
    for (int k = 0; k < 64; ++k) {
      uint32_t wv = W1h[k*64 + j];
      #pragma unroll
      for (int m = 0; m < 8; ++m) {
        int st = w + 8*m;
        acc[m] = fdot2_(wv, dech2[st >> 5][st & 31][k], acc[m]);
      }
    }
    #pragma unroll
    for (int m = 0; m < 8; ++m) {
      int st = w + 8*m;
      hidf[st][j] = fmaxf(acc[m], 0.0f);
    }
  }
  __syncthreads();
  if (tid < 128) {
    int st = tid >> 1, e = tid & 1;
    float acc = b2[e];
    #pragma unroll 16
    for (int j = 0; j < 64; ++j) acc += W2[e*64 + j] * hidf[st][j];
    int s = st >> 5, t = st & 31;
    out_kp[((bn0 + s)*32 + t)*2 + e] = acc;
  }
}

// ---------------------------------------------------------------------------
// Launch
// ---------------------------------------------------------------------------
extern "C" void kernel_launch(void* const* d_in, const int* in_sizes, int n_in,
                              void* d_out, int out_size, void* d_ws, size_t ws_size,
                              hipStream_t stream) {
  const float* x          = (const float*)d_in[0];
  const float* mask_point = (const float*)d_in[1];
  const int*   point_mask = (const int*)d_in[2];
  const float* conv1_w    = (const float*)d_in[3];
  const float* conv1_b    = (const float*)d_in[4];
  const float* conv2_w    = (const float*)d_in[5];
  const float* conv2_b    = (const float*)d_in[6];
  const float* Wih_e      = (const float*)d_in[7];
  const float* Whh_e      = (const float*)d_in[8];
  const float* bih_e      = (const float*)d_in[9];
  const float* bhh_e      = (const float*)d_in[10];
  const float* Wih_d      = (const float*)d_in[11];
  const float* Whh_d      = (const float*)d_in[12];
  const float* bih_d      = (const float*)d_in[13];
  const float* bhh_d      = (const float*)d_in[14];
  const float* W1         = (const float*)d_in[15];
  const float* b1         = (const float*)d_in[16];
  const float* W2         = (const float*)d_in[17];
  const float* b2         = (const float*)d_in[18];

  float* out = (float*)d_out;
  char*  ws  = (char*)d_ws;

  const bool use_xt = (ws_size >= WS_NEED_XT);

  prep_kernel<<<(PREP_TOTAL + 255)/256, 256, 0, stream>>>(
      Wih_e, Whh_e, bih_e, bhh_e, Wih_d, Whh_d, bih_d, bhh_d,
      conv1_w, conv2_w, W1, ws, use_xt ? 1 : 0);

  points_kernel<<<64, 256, 0, stream>>>(
      mask_point, out + 32768, (int*)(ws + OFF_FLAT));

  if (use_xt) {
    transpose_kernel<<<1024, 256, 0, stream>>>(x, (uint32_t*)(ws + OFF_XT));
    conv_gather_kernel<1><<<512, 256, 0, stream>>>(
        x, (const uint32_t*)(ws + OFF_XT), point_mask, conv1_b, conv2_b,
        ws, (_Float16*)(ws + OFF_DOTS), (const int*)(ws + OFF_FLAT));
  } else {
    conv_gather_kernel<0><<<512, 256, 0, stream>>>(
        x, nullptr, point_mask, conv1_b, conv2_b,
        ws, (_Float16*)(ws + OFF_DOTS), (const int*)(ws + OFF_FLAT));
  }

  lstm_head_kernel<<<256, 512, 0, stream>>>(
      ws, b1, W2, b2, out);
}